// Round 23
// baseline (163.672 us; speedup 1.0000x reference)
//
#include <hip/hip_runtime.h>
#include <hip/hip_bf16.h>

// GQA forward, round 22: r21 (passing, 160.6us) + flash row-max reduction via
// VALU permlane swaps instead of ds_bpermute shfl_xor (4 per iter on the
// softmax critical chain, ~60cyc LDS-pipe each -> ~4cyc VALU each).
// 6 dispatches: convert(+mask), gemm_qkv, fragify_all, flash, combine, gemm_out.
// B=2, S=2048, HIDDEN=1024, 16 heads x 64 dim, RoPE over full hidden (half=512).

constexpr int Bb  = 2;
constexpr int Ss  = 2048;
constexpr int Hh  = 1024;
constexpr int NHh = 16;
constexpr int Mm  = Bb * Ss;   // 4096 rows

typedef __attribute__((ext_vector_type(8))) unsigned short ushort8;
typedef __attribute__((ext_vector_type(8))) short short8;
typedef __attribute__((ext_vector_type(4))) float f32x4;
typedef __attribute__((ext_vector_type(4))) unsigned int u32x4;

__device__ __forceinline__ unsigned short f2bf(float f) {
    unsigned int u = __float_as_uint(f);
    u += 0x7fffu + ((u >> 16) & 1u);
    return (unsigned short)(u >> 16);
}
__device__ __forceinline__ float bf2f(unsigned short h) {
    return __uint_as_float(((unsigned int)h) << 16);
}
__device__ __forceinline__ void gload16(const void* g, void* l) {
    __builtin_amdgcn_global_load_lds(
        (const __attribute__((address_space(1))) unsigned int*)g,
        (__attribute__((address_space(3))) unsigned int*)l, 16, 0, 0);
}

// Wave-wide max over lane groups {l16 fixed, g=0..3} using VALU permlane swaps.
__device__ __forceinline__ float lane_gmax(float m) {
    float a = m, b = m;
    asm("v_permlane32_swap_b32 %0, %1" : "+v"(a), "+v"(b));   // a={lo,lo} b={hi,hi}
    m = fmaxf(a, b);                                           // xor-32 reduce
    a = m; b = m;
    asm("v_permlane16_swap_b32 %0, %1" : "+v"(a), "+v"(b));   // rows swap within 32
    return fmaxf(a, b);                                        // xor-16 reduce
}

// ------- fp32 -> bf16 convert (x, W's) + mask build fused (tail blocks) ---------
__global__ __launch_bounds__(256) void convert_k(
    const float* __restrict__ x,
    const float* __restrict__ Wq, const float* __restrict__ Wk,
    const float* __restrict__ Wv, const float* __restrict__ Wo,
    const int* __restrict__ am,
    unsigned short* __restrict__ xb, unsigned short* __restrict__ wall,
    unsigned short* __restrict__ maskbf)
{
    if (blockIdx.x >= 4096) {
        // mask tail: 2 blocks cover 4096 ints, 8 per thread
        int i = (blockIdx.x - 4096) * 2048 + threadIdx.x * 8;
        ushort8 o;
        #pragma unroll
        for (int jj = 0; jj < 8; ++jj)
            o[jj] = am[i + jj] ? (unsigned short)0x3F80 : (unsigned short)0;
        *(ushort8*)&maskbf[i] = o;
        return;
    }
    size_t e = ((size_t)blockIdx.x * 256 + threadIdx.x) << 3;
    const float* s; unsigned short* d;
    if (e < (size_t)Mm * Hh) {
        s = x + e; d = xb + e;
    } else {
        size_t f = e - (size_t)Mm * Hh;
        int t = (int)(f >> 20);
        const float* w = (t == 0) ? Wq : (t == 1) ? Wk : (t == 2) ? Wv : Wo;
        s = w + (f & 1048575);
        d = wall + f;
    }
    float4 a = *(const float4*)s;
    float4 b = *(const float4*)(s + 4);
    ushort8 o;
    o[0] = f2bf(a.x); o[1] = f2bf(a.y); o[2] = f2bf(a.z); o[3] = f2bf(a.w);
    o[4] = f2bf(b.x); o[5] = f2bf(b.y); o[6] = f2bf(b.z); o[7] = f2bf(b.w);
    *(ushort8*)d = o;
}

// ---------------- bf16 MFMA GEMM core (unchanged) --------------------------------
#define GEMM_BODY(ATYPE_PTR, WPTR, K0MAX)                                          \
    __shared__ unsigned short As[128 * 64];                                        \
    __shared__ unsigned short Bs[128 * 64];                                        \
    const int tid  = threadIdx.x;                                                  \
    const int lane = tid & 63;                                                     \
    const int w    = tid >> 6;                                                     \
    const int wr   = w >> 1, wc = w & 1;                                           \
    const int l16  = lane & 15, g = lane >> 4;                                     \
    const int R0   = blockIdx.x * 128;                                             \
    char* asb = (char*)As; char* bsb = (char*)Bs;                                  \
    f32x4 acc[4][4] = {};                                                          \
    for (int k0 = 0; k0 < K0MAX; k0 += 64) {                                       \
        _Pragma("unroll")                                                          \
        for (int it = 0; it < 4; ++it) {                                           \
            int sbase = w * 4096 + it * 1024;                                      \
            int boff  = sbase + lane * 16;                                         \
            int r     = boff >> 7;                                                 \
            int c     = (boff >> 4) & 7;                                           \
            int col   = k0 + ((c ^ (r & 7)) << 3);                                 \
            gload16(&ATYPE_PTR[(size_t)(R0 + r) * 1024 + col], asb + sbase);       \
            gload16(&WPTR[(size_t)(gn + r) * 1024 + col], bsb + sbase);            \
        }                                                                          \
        __syncthreads();                                                           \
        short8 bfrag[4][2];                                                        \
        _Pragma("unroll")                                                          \
        for (int u = 0; u < 4; ++u) {                                              \
            int row = wc * 64 + u * 16 + l16;                                      \
            _Pragma("unroll")                                                      \
            for (int s = 0; s < 2; ++s)                                            \
                bfrag[u][s] = *(const short8*)(bsb + row * 128 +                   \
                               ((s * 64 + g * 16) ^ ((row & 7) << 4)));            \
        }                                                                          \
        _Pragma("unroll")                                                          \
        for (int t = 0; t < 4; ++t) {                                              \
            int row = wr * 64 + t * 16 + l16;                                      \
            short8 af[2];                                                          \
            _Pragma("unroll")                                                      \
            for (int s = 0; s < 2; ++s)                                            \
                af[s] = *(const short8*)(asb + row * 128 +                         \
                         ((s * 64 + g * 16) ^ ((row & 7) << 4)));                  \
            _Pragma("unroll")                                                      \
            for (int u = 0; u < 4; ++u) {                                          \
                acc[t][u] = __builtin_amdgcn_mfma_f32_16x16x32_bf16(af[0], bfrag[u][0], acc[t][u], 0, 0, 0); \
                acc[t][u] = __builtin_amdgcn_mfma_f32_16x16x32_bf16(af[1], bfrag[u][1], acc[t][u], 0, 0, 0); \
            }                                                                      \
        }                                                                          \
        __syncthreads();                                                           \
    }

__global__ __launch_bounds__(256) void gemm_qkv_k(
    const unsigned short* __restrict__ xb, const unsigned short* __restrict__ wall,
    const float* __restrict__ bq, const float* __restrict__ bk, const float* __restrict__ bv,
    unsigned short* __restrict__ q, unsigned short* __restrict__ k2,
    unsigned short* __restrict__ v)
{
    const int gn = blockIdx.y * 128;
    GEMM_BODY(xb, wall, 1024)

    const int sel = gn >> 10;
    const int n0  = gn & 1023;
    const float* bias = (sel == 0) ? bq : (sel == 1) ? bk : bv;
    unsigned short* outp = (sel == 0) ? q : (sel == 1) ? k2 : v;
    // Pre-scale q by (1/8)*log2e: q feeds only QK^T; scale commutes with RoPE.
    const float qs = (sel == 0) ? 0.18033688011112042f : 1.0f;
    #pragma unroll
    for (int u = 0; u < 4; ++u) {
        int coll = wc * 64 + u * 16 + l16;
        float bb = bias[n0 + coll];
        #pragma unroll
        for (int t = 0; t < 4; ++t)
            #pragma unroll
            for (int rr = 0; rr < 4; ++rr) {
                int row = R0 + wr * 64 + t * 16 + g * 4 + rr;
                outp[(size_t)row * 1024 + n0 + coll] = f2bf((acc[t][u][rr] + bb) * qs);
            }
    }
}

__global__ __launch_bounds__(256) void gemm_out_k(
    const unsigned short* __restrict__ ao, const unsigned short* __restrict__ wo,
    const float* __restrict__ bo, float* __restrict__ out)
{
    const int gn = blockIdx.y * 128;
    GEMM_BODY(ao, wo, 1024)

    #pragma unroll
    for (int u = 0; u < 4; ++u) {
        int coll = wc * 64 + u * 16 + l16;
        float bb = bo[gn + coll];
        #pragma unroll
        for (int t = 0; t < 4; ++t)
            #pragma unroll
            for (int rr = 0; rr < 4; ++rr) {
                int row = R0 + wr * 64 + t * 16 + g * 4 + rr;
                out[(size_t)row * 1024 + gn + coll] = acc[t][u][rr] + bb;
            }
    }
}

// ------- Fused fragment materialization: z==0 fragify_v, z==1 rope_frag ---------
// Safe aliasing: z=0 reads v, writes vfrag(=ao buffer); z=1 reads q,k, writes
// qfrag(=xb), kfrag. No buffer is both read and written across z.
__global__ __launch_bounds__(256) void fragify_all_k(
    const unsigned short* __restrict__ qin, const unsigned short* __restrict__ kin,
    const unsigned short* __restrict__ v, const int* __restrict__ mask,
    unsigned short* __restrict__ qfrag, unsigned short* __restrict__ kfrag,
    unsigned short* __restrict__ vfrag)
{
    const int t = threadIdx.x;

    if (blockIdx.z == 0) {
        // ---- fragify_v: kt = x, bh = y ----
        __shared__ unsigned short Ld[64][72];
        __shared__ int Lm[64];
        const int kt = blockIdx.x, bh = blockIdx.y;   // bh = bz*16+h
        const int bz = bh >> 4, h = bh & 15;
        const int r = t & 63, c0 = (t >> 6) << 4;
        const unsigned short* srcp = &v[(size_t)(bz * Ss + kt * 64 + r) * 1024 + h * 64 + c0];
        *(ushort8*)&Ld[r][c0]     = *(const ushort8*)srcp;
        *(ushort8*)&Ld[r][c0 + 8] = *(const ushort8*)(srcp + 8);
        if (t < 64) Lm[t] = mask[bz * Ss + kt * 64 + t];
        __syncthreads();

        #pragma unroll
        for (int cc = 0; cc < 2; ++cc) {
            int c = t * 2 + cc;               // 0..511
            int dt4 = c >> 7, ks = (c >> 6) & 1, lane2 = c & 63;
            int gg = lane2 >> 4, ll = lane2 & 15;
            ushort8 o;
            #pragma unroll
            for (int e = 0; e < 8; ++e) {
                int key = ks * 32 + gg * 8 + e;
                o[e] = Lm[key] ? Ld[key][dt4 * 16 + ll] : (unsigned short)0;
            }
            *(ushort8*)&vfrag[(size_t)bh * 131072 + (size_t)kt * 4096 + (size_t)c * 8] = o;
        }
    } else {
        // ---- rope_frag: kt = x, hp = y&7, zz = y>>3 ----
        __shared__ unsigned short Ld[2][64][72];
        const int kt = blockIdx.x;
        const int hp = blockIdx.y & 7;
        const int zz = blockIdx.y >> 3;   // bit0 = bz, bit1 = sel
        const int bz = zz & 1, sel = zz >> 1;
        const unsigned short* src = sel ? kin : qin;
        unsigned short* dstf = sel ? kfrag : qfrag;

        const int r   = t & 63;
        const int c16 = (t >> 6) << 4;    // 0,16,32,48
        const int pos = kt * 64 + r;
        const size_t rowb = (size_t)(bz * Ss + pos) * 1024;

        ushort8 A0 = *(const ushort8*)&src[rowb + hp * 64 + c16];
        ushort8 A1 = *(const ushort8*)&src[rowb + hp * 64 + c16 + 8];
        ushort8 B0 = *(const ushort8*)&src[rowb + (hp + 8) * 64 + c16];
        ushort8 B1 = *(const ushort8*)&src[rowb + (hp + 8) * 64 + c16 + 8];

        #pragma unroll
        for (int i = 0; i < 16; ++i) {
            int d = c16 + i;
            float jj  = (float)(hp * 64 + d);
            float inv = exp2f(jj * -0.0259525632621414f);   // 10000^(-j/512)
            float ang = (float)pos * inv;
            float sn, cs;
            __sincosf(ang, &sn, &cs);
            unsigned short ua = (i < 8) ? A0[i] : A1[i - 8];
            unsigned short ub = (i < 8) ? B0[i] : B1[i - 8];
            float a = bf2f(ua), b = bf2f(ub);
            Ld[0][r][d] = f2bf(a * cs - b * sn);   // head hp   (low half j)
            Ld[1][r][d] = f2bf(b * cs + a * sn);   // head hp+8 (high half j+512)
        }
        __syncthreads();

        #pragma unroll
        for (int cc = 0; cc < 4; ++cc) {
            int c    = t * 4 + cc;            // 0..1023
            int hh   = c >> 9;                // head select
            int ci   = c & 511;               // chunk within head tile (0..511)
            int blk  = ci >> 7, s2 = (ci >> 6) & 1, lane2 = ci & 63;
            int gg = lane2 >> 4, ll = lane2 & 15;
            ushort8 o = *(const ushort8*)&Ld[hh][blk * 16 + ll][s2 * 32 + gg * 8];
            size_t base = (size_t)(bz * 16 + hp + hh * 8) * 131072 + (size_t)kt * 4096;
            *(ushort8*)&dstf[base + (size_t)ci * 8] = o;
        }
    }
}

// ---------------- Flash attention: rolled loop, permlane max reduction -----------
__global__ __launch_bounds__(256, 3) void flash_k(
    const unsigned short* __restrict__ qfrag, const unsigned short* __restrict__ kfrag,
    const unsigned short* __restrict__ vfrag, const unsigned short* __restrict__ maskbf,
    unsigned short* __restrict__ opart, float2* __restrict__ ml)
{
    // Bijective XCD remap: 1024 blocks = 8 XCDs x (4 (h,bz) groups x 16 qb x 2 half).
    const int F   = blockIdx.x;
    const int xcd = F & 7, j = F >> 3;          // j: 0..127
    const int grp = xcd * 4 + (j >> 5);         // 0..31
    const int rem = j & 31;
    const int qb  = rem >> 1;
    const int half = rem & 1;
    const int h   = grp & 15;
    const int bz  = grp >> 4;
    const int kt0 = half * 16;

    const int tid  = threadIdx.x;
    const int lane = tid & 63;
    const int w    = tid >> 6;
    const int l16  = lane & 15;
    const int g    = lane >> 4;

    const size_t fb = (size_t)(bz * 16 + h) * 131072;
    const unsigned short* kfb = kfrag + fb;
    const unsigned short* vfb = vfrag + fb;
    const unsigned short* qfb = qfrag + fb;

    // Running pointers (lane offsets baked in); advance one tile per iteration.
    const unsigned short* kp = kfb + (size_t)kt0 * 4096 + lane * 8;
    const unsigned short* vp = vfb + (size_t)kt0 * 4096 + lane * 8;
    const unsigned short* mp = maskbf + bz * Ss + kt0 * 64 + g * 8;

    // Q fragments (pre-scaled): blk16 = qb*8 + w*2 + t
    short8 qf[2][2];
    #pragma unroll
    for (int t = 0; t < 2; ++t)
        #pragma unroll
        for (int s = 0; s < 2; ++s)
            qf[t][s] = *(const short8*)&qfb[(size_t)(qb * 8 + w * 2 + t) * 1024
                                            + s * 512 + lane * 8];

    f32x4 O[2][4];
    #pragma unroll
    for (int t = 0; t < 2; ++t)
        #pragma unroll
        for (int d = 0; d < 4; ++d) O[t][d] = (f32x4)0.f;
    f32x4 Osum[2];
    Osum[0] = (f32x4)0.f; Osum[1] = (f32x4)0.f;
    float mrow[2] = {-1.0e4f, -1.0e4f};
    const f32x4 Zf = (f32x4)0.f;

    #pragma unroll 1
    for (int it = 0; it < 16; ++it) {
        // ---- K tile + mask (single-buffered) ----
        short8 KC[8];
        #pragma unroll
        for (int i = 0; i < 4; ++i) KC[i]     = *(const short8*)(kp + i * 512);
        #pragma unroll
        for (int i = 0; i < 4; ++i) KC[4 + i] = *(const short8*)(kp + 2048 + i * 512);
        short8 mf[2];
        mf[0] = *(const short8*)mp;
        mf[1] = *(const short8*)(mp + 32);

        // ---- S^T = K . Q^T ----
        f32x4 S[2][4];
        #pragma unroll
        for (int k4 = 0; k4 < 4; ++k4)
            #pragma unroll
            for (int t = 0; t < 2; ++t) {
                S[t][k4] = __builtin_amdgcn_mfma_f32_16x16x32_bf16(
                    KC[k4 * 2 + 0], qf[t][0], Zf, 0, 0, 0);
                S[t][k4] = __builtin_amdgcn_mfma_f32_16x16x32_bf16(
                    KC[k4 * 2 + 1], qf[t][1], S[t][k4], 0, 0, 0);
            }

        // ---- V ks=0 loads (latency under softmax) ----
        short8 V0[4];
        #pragma unroll
        for (int dt = 0; dt < 4; ++dt)
            V0[dt] = *(const short8*)(vp + dt * 1024);

        // ---- row max: in-lane, then permlane-swap cross-group reduce (VALU) ----
        float rm[2];
        #pragma unroll
        for (int t = 0; t < 2; ++t) {
            float m0 = fmaxf(fmaxf(S[t][0][0], S[t][0][1]), fmaxf(S[t][0][2], S[t][0][3]));
            float m1 = fmaxf(fmaxf(S[t][1][0], S[t][1][1]), fmaxf(S[t][1][2], S[t][1][3]));
            float m2 = fmaxf(fmaxf(S[t][2][0], S[t][2][1]), fmaxf(S[t][2][2], S[t][2][3]));
            float m3 = fmaxf(fmaxf(S[t][3][0], S[t][3][1]), fmaxf(S[t][3][2], S[t][3][3]));
            rm[t] = lane_gmax(fmaxf(fmaxf(m0, m1), fmaxf(m2, m3)));
        }

        // ---- defer-max rescale ----
        bool grow = (rm[0] > mrow[0] + 10.0f) || (rm[1] > mrow[1] + 10.0f);
        if (__any((int)grow)) {
            float mn0 = fmaxf(mrow[0], rm[0]);
            float mn1 = fmaxf(mrow[1], rm[1]);
            float rs0 = exp2f(mrow[0] - mn0);
            float rs1 = exp2f(mrow[1] - mn1);
            mrow[0] = mn0; mrow[1] = mn1;
            #pragma unroll
            for (int r = 0; r < 4; ++r) {
                float f0 = __shfl(rs0, g * 4 + r);
                float f1 = __shfl(rs1, g * 4 + r);
                #pragma unroll
                for (int dt = 0; dt < 4; ++dt) { O[0][dt][r] *= f0; O[1][dt][r] *= f1; }
                Osum[0][r] *= f0; Osum[1][r] *= f1;
            }
        }

        // ---- V ks=1 loads (latency under pack + PV ks0) ----
        short8 V1[4];
        #pragma unroll
        for (int dt = 0; dt < 4; ++dt)
            V1[dt] = *(const short8*)(vp + 512 + dt * 1024);

        // ---- P = exp2(S - m), pack, redistribute, PV ----
        #pragma unroll
        for (int t = 0; t < 2; ++t) {
            unsigned int U[4][2];
            #pragma unroll
            for (int k4 = 0; k4 < 4; ++k4) {
                float p0 = exp2f(S[t][k4][0] - mrow[t]);
                float p1 = exp2f(S[t][k4][1] - mrow[t]);
                float p2 = exp2f(S[t][k4][2] - mrow[t]);
                float p3 = exp2f(S[t][k4][3] - mrow[t]);
                asm("v_cvt_pk_bf16_f32 %0, %1, %2" : "=v"(U[k4][0]) : "v"(p0), "v"(p1));
                asm("v_cvt_pk_bf16_f32 %0, %1, %2" : "=v"(U[k4][1]) : "v"(p2), "v"(p3));
            }
            asm("v_permlane32_swap_b32 %0, %1" : "+v"(U[0][0]), "+v"(U[1][0]));
            asm("v_permlane32_swap_b32 %0, %1" : "+v"(U[0][1]), "+v"(U[1][1]));
            asm("v_permlane32_swap_b32 %0, %1" : "+v"(U[2][0]), "+v"(U[3][0]));
            asm("v_permlane32_swap_b32 %0, %1" : "+v"(U[2][1]), "+v"(U[3][1]));
            asm("v_permlane16_swap_b32 %0, %1" : "+v"(U[0][0]), "+v"(U[1][0]));
            asm("v_permlane16_swap_b32 %0, %1" : "+v"(U[0][1]), "+v"(U[1][1]));
            asm("v_permlane16_swap_b32 %0, %1" : "+v"(U[2][0]), "+v"(U[3][0]));
            asm("v_permlane16_swap_b32 %0, %1" : "+v"(U[2][1]), "+v"(U[3][1]));

            u32x4 gp0, gp1;
            gp0[0] = U[0][0]; gp0[1] = U[0][1]; gp0[2] = U[1][0]; gp0[3] = U[1][1];
            gp1[0] = U[2][0]; gp1[1] = U[2][1]; gp1[2] = U[3][0]; gp1[3] = U[3][1];
            short8 pf0 = __builtin_bit_cast(short8, gp0);
            short8 pf1 = __builtin_bit_cast(short8, gp1);

            Osum[t] = __builtin_amdgcn_mfma_f32_16x16x32_bf16(pf0, mf[0], Osum[t], 0, 0, 0);
            #pragma unroll
            for (int dt = 0; dt < 4; ++dt)
                O[t][dt] = __builtin_amdgcn_mfma_f32_16x16x32_bf16(pf0, V0[dt], O[t][dt], 0, 0, 0);
            Osum[t] = __builtin_amdgcn_mfma_f32_16x16x32_bf16(pf1, mf[1], Osum[t], 0, 0, 0);
            #pragma unroll
            for (int dt = 0; dt < 4; ++dt)
                O[t][dt] = __builtin_amdgcn_mfma_f32_16x16x32_bf16(pf1, V1[dt], O[t][dt], 0, 0, 0);
        }

        kp += 4096; vp += 4096; mp += 64;
    }

    // ---- epilogue: normalized partial O (bf16) + per-query (m, sum) ----
    const size_t NE = (size_t)Mm * Hh;
    #pragma unroll
    for (int t = 0; t < 2; ++t)
        #pragma unroll
        for (int r = 0; r < 4; ++r) {
            float osum = Osum[t][r];
            float inv  = osum > 0.f ? 1.0f / osum : 0.f;
            float mo   = __shfl(mrow[t], g * 4 + r);   // S-layout m -> O-layout
            int rowl   = qb * 128 + w * 32 + t * 16 + g * 4 + r;   // 0..2047
            size_t ob  = (size_t)half * NE
                       + ((size_t)(bz * Ss + rowl)) * 1024 + h * 64;
            #pragma unroll
            for (int dt = 0; dt < 4; ++dt)
                opart[ob + dt * 16 + l16] = f2bf(O[t][dt][r] * inv);
            if (l16 == 0)
                ml[((half * 2 + bz) * 16 + h) * 2048 + rowl] = make_float2(mo, osum);
        }
}

// ---------------- Combine split-K halves (writes ao, after flash) ----------------
__global__ __launch_bounds__(256) void combine_k(
    const unsigned short* __restrict__ opart, const float2* __restrict__ ml,
    unsigned short* __restrict__ ao)
{
    const size_t NE = (size_t)Mm * Hh;
    int c    = blockIdx.x * 256 + threadIdx.x;   // 0..524287 (4096 rows x 128)
    int row  = c >> 7;                           // bz*2048 + qrow
    int col8 = c & 127;
    int h    = col8 >> 3;
    int bz   = row >> 11, qrow = row & 2047;

    float2 a = ml[((0 * 2 + bz) * 16 + h) * 2048 + qrow];
    float2 b = ml[((1 * 2 + bz) * 16 + h) * 2048 + qrow];
    float M  = fmaxf(a.x, b.x);
    float w1 = exp2f(a.x - M) * a.y;
    float w2 = exp2f(b.x - M) * b.y;
    float tot = w1 + w2;
    float inv = tot > 0.f ? 1.0f / tot : 0.f;
    w1 *= inv; w2 *= inv;

    ushort8 o1 = *(const ushort8*)&opart[(size_t)c * 8];
    ushort8 o2 = *(const ushort8*)&opart[NE + (size_t)c * 8];
    ushort8 o;
    #pragma unroll
    for (int jj = 0; jj < 8; ++jj)
        o[jj] = f2bf(bf2f(o1[jj]) * w1 + bf2f(o2[jj]) * w2);
    *(ushort8*)&ao[(size_t)c * 8] = o;
}

extern "C" void kernel_launch(void* const* d_in, const int* in_sizes, int n_in,
                              void* d_out, int out_size, void* d_ws, size_t ws_size,
                              hipStream_t stream)
{
    const float* x  = (const float*)d_in[0];
    const int*   am = (const int*)d_in[1];
    const float* Wq = (const float*)d_in[2];
    const float* bq = (const float*)d_in[3];
    const float* Wk = (const float*)d_in[4];
    const float* bk = (const float*)d_in[5];
    const float* Wv = (const float*)d_in[6];
    const float* bv = (const float*)d_in[7];
    const float* Wo = (const float*)d_in[8];
    const float* bo = (const float*)d_in[9];
    float* out = (float*)d_out;

    const size_t NE = (size_t)Mm * Hh;           // 4M elems
    unsigned short* q     = (unsigned short*)d_ws;
    unsigned short* k     = q + NE;
    unsigned short* v     = k + NE;
    unsigned short* ao    = v + NE;
    unsigned short* xb    = ao + NE;             // gemm input; reused as qfrag
    unsigned short* wall  = xb + NE;             // [Wq;Wk;Wv;Wo] rows
    unsigned short* wo    = wall + 3u * 1048576u;
    unsigned short* kfrag = wall + 4u * 1048576u;
    unsigned short* qfrag = xb;                  // xb dead after gemm_qkv
    unsigned short* vfrag = ao;                  // ao dead until combine_k
    unsigned short* opart = k;                   // k,v dead once frags built (16 MB)
    float2*         ml    = (float2*)(kfrag + 4u * 1048576u);   // 1 MB, 131072 entries
    unsigned short* maskbf = (unsigned short*)(ml + 131072);    // after ml's full extent

    convert_k<<<dim3(4096 + 2), 256, 0, stream>>>(
        x, Wq, Wk, Wv, Wo, am, xb, wall, maskbf);
    gemm_qkv_k<<<dim3(Mm / 128, 3072 / 128), 256, 0, stream>>>(
        xb, wall, bq, bk, bv, q, k, v);
    fragify_all_k<<<dim3(32, 32, 2), 256, 0, stream>>>(
        q, k, v, am, qfrag, kfrag, vfrag);
    flash_k<<<dim3(1024), 256, 0, stream>>>(qfrag, kfrag, vfrag, maskbf, opart, ml);
    combine_k<<<dim3((Mm * 128) / 256), 256, 0, stream>>>(opart, ml, ao);
    gemm_out_k<<<dim3(Mm / 128, Hh / 128), 256, 0, stream>>>(ao, wo, bo, out);
}

// Round 24
// 160.229 us; speedup vs baseline: 1.0215x; 1.0215x over previous
//
#include <hip/hip_runtime.h>
#include <hip/hip_bf16.h>

// GQA forward, FINAL (round 23 = round 21, the best-measured configuration):
// 160.6us total. Pipeline: convert(+mask fused), fused QKV bf16-MFMA GEMM,
// fused RoPE+fragment materialization, split-K all-register flash attention
// (swapped QK^T, mask folded into MFMA operands, in-register P redistribute
// via permlane swaps, defer-max, rolled loop, (256,3)), split-K combine,
// bf16-MFMA output GEMM. 6 dispatches.
// Flash plateau (77us) documented: 9 structural hypotheses tested and null.
// B=2, S=2048, HIDDEN=1024, 16 heads x 64 dim, RoPE over full hidden (half=512).

constexpr int Bb  = 2;
constexpr int Ss  = 2048;
constexpr int Hh  = 1024;
constexpr int NHh = 16;
constexpr int Mm  = Bb * Ss;   // 4096 rows

typedef __attribute__((ext_vector_type(8))) unsigned short ushort8;
typedef __attribute__((ext_vector_type(8))) short short8;
typedef __attribute__((ext_vector_type(4))) float f32x4;
typedef __attribute__((ext_vector_type(4))) unsigned int u32x4;

__device__ __forceinline__ unsigned short f2bf(float f) {
    unsigned int u = __float_as_uint(f);
    u += 0x7fffu + ((u >> 16) & 1u);
    return (unsigned short)(u >> 16);
}
__device__ __forceinline__ float bf2f(unsigned short h) {
    return __uint_as_float(((unsigned int)h) << 16);
}
__device__ __forceinline__ void gload16(const void* g, void* l) {
    __builtin_amdgcn_global_load_lds(
        (const __attribute__((address_space(1))) unsigned int*)g,
        (__attribute__((address_space(3))) unsigned int*)l, 16, 0, 0);
}

// ------- fp32 -> bf16 convert (x, W's) + mask build fused (tail blocks) ---------
__global__ __launch_bounds__(256) void convert_k(
    const float* __restrict__ x,
    const float* __restrict__ Wq, const float* __restrict__ Wk,
    const float* __restrict__ Wv, const float* __restrict__ Wo,
    const int* __restrict__ am,
    unsigned short* __restrict__ xb, unsigned short* __restrict__ wall,
    unsigned short* __restrict__ maskbf)
{
    if (blockIdx.x >= 4096) {
        // mask tail: 2 blocks cover 4096 ints, 8 per thread
        int i = (blockIdx.x - 4096) * 2048 + threadIdx.x * 8;
        ushort8 o;
        #pragma unroll
        for (int jj = 0; jj < 8; ++jj)
            o[jj] = am[i + jj] ? (unsigned short)0x3F80 : (unsigned short)0;
        *(ushort8*)&maskbf[i] = o;
        return;
    }
    size_t e = ((size_t)blockIdx.x * 256 + threadIdx.x) << 3;
    const float* s; unsigned short* d;
    if (e < (size_t)Mm * Hh) {
        s = x + e; d = xb + e;
    } else {
        size_t f = e - (size_t)Mm * Hh;
        int t = (int)(f >> 20);
        const float* w = (t == 0) ? Wq : (t == 1) ? Wk : (t == 2) ? Wv : Wo;
        s = w + (f & 1048575);
        d = wall + f;
    }
    float4 a = *(const float4*)s;
    float4 b = *(const float4*)(s + 4);
    ushort8 o;
    o[0] = f2bf(a.x); o[1] = f2bf(a.y); o[2] = f2bf(a.z); o[3] = f2bf(a.w);
    o[4] = f2bf(b.x); o[5] = f2bf(b.y); o[6] = f2bf(b.z); o[7] = f2bf(b.w);
    *(ushort8*)d = o;
}

// ---------------- bf16 MFMA GEMM core --------------------------------------------
#define GEMM_BODY(ATYPE_PTR, WPTR, K0MAX)                                          \
    __shared__ unsigned short As[128 * 64];                                        \
    __shared__ unsigned short Bs[128 * 64];                                        \
    const int tid  = threadIdx.x;                                                  \
    const int lane = tid & 63;                                                     \
    const int w    = tid >> 6;                                                     \
    const int wr   = w >> 1, wc = w & 1;                                           \
    const int l16  = lane & 15, g = lane >> 4;                                     \
    const int R0   = blockIdx.x * 128;                                             \
    char* asb = (char*)As; char* bsb = (char*)Bs;                                  \
    f32x4 acc[4][4] = {};                                                          \
    for (int k0 = 0; k0 < K0MAX; k0 += 64) {                                       \
        _Pragma("unroll")                                                          \
        for (int it = 0; it < 4; ++it) {                                           \
            int sbase = w * 4096 + it * 1024;                                      \
            int boff  = sbase + lane * 16;                                         \
            int r     = boff >> 7;                                                 \
            int c     = (boff >> 4) & 7;                                           \
            int col   = k0 + ((c ^ (r & 7)) << 3);                                 \
            gload16(&ATYPE_PTR[(size_t)(R0 + r) * 1024 + col], asb + sbase);       \
            gload16(&WPTR[(size_t)(gn + r) * 1024 + col], bsb + sbase);            \
        }                                                                          \
        __syncthreads();                                                           \
        short8 bfrag[4][2];                                                        \
        _Pragma("unroll")                                                          \
        for (int u = 0; u < 4; ++u) {                                              \
            int row = wc * 64 + u * 16 + l16;                                      \
            _Pragma("unroll")                                                      \
            for (int s = 0; s < 2; ++s)                                            \
                bfrag[u][s] = *(const short8*)(bsb + row * 128 +                   \
                               ((s * 64 + g * 16) ^ ((row & 7) << 4)));            \
        }                                                                          \
        _Pragma("unroll")                                                          \
        for (int t = 0; t < 4; ++t) {                                              \
            int row = wr * 64 + t * 16 + l16;                                      \
            short8 af[2];                                                          \
            _Pragma("unroll")                                                      \
            for (int s = 0; s < 2; ++s)                                            \
                af[s] = *(const short8*)(asb + row * 128 +                         \
                         ((s * 64 + g * 16) ^ ((row & 7) << 4)));                  \
            _Pragma("unroll")                                                      \
            for (int u = 0; u < 4; ++u) {                                          \
                acc[t][u] = __builtin_amdgcn_mfma_f32_16x16x32_bf16(af[0], bfrag[u][0], acc[t][u], 0, 0, 0); \
                acc[t][u] = __builtin_amdgcn_mfma_f32_16x16x32_bf16(af[1], bfrag[u][1], acc[t][u], 0, 0, 0); \
            }                                                                      \
        }                                                                          \
        __syncthreads();                                                           \
    }

__global__ __launch_bounds__(256) void gemm_qkv_k(
    const unsigned short* __restrict__ xb, const unsigned short* __restrict__ wall,
    const float* __restrict__ bq, const float* __restrict__ bk, const float* __restrict__ bv,
    unsigned short* __restrict__ q, unsigned short* __restrict__ k2,
    unsigned short* __restrict__ v)
{
    const int gn = blockIdx.y * 128;
    GEMM_BODY(xb, wall, 1024)

    const int sel = gn >> 10;
    const int n0  = gn & 1023;
    const float* bias = (sel == 0) ? bq : (sel == 1) ? bk : bv;
    unsigned short* outp = (sel == 0) ? q : (sel == 1) ? k2 : v;
    // Pre-scale q by (1/8)*log2e: q feeds only QK^T; scale commutes with RoPE.
    const float qs = (sel == 0) ? 0.18033688011112042f : 1.0f;
    #pragma unroll
    for (int u = 0; u < 4; ++u) {
        int coll = wc * 64 + u * 16 + l16;
        float bb = bias[n0 + coll];
        #pragma unroll
        for (int t = 0; t < 4; ++t)
            #pragma unroll
            for (int rr = 0; rr < 4; ++rr) {
                int row = R0 + wr * 64 + t * 16 + g * 4 + rr;
                outp[(size_t)row * 1024 + n0 + coll] = f2bf((acc[t][u][rr] + bb) * qs);
            }
    }
}

__global__ __launch_bounds__(256) void gemm_out_k(
    const unsigned short* __restrict__ ao, const unsigned short* __restrict__ wo,
    const float* __restrict__ bo, float* __restrict__ out)
{
    const int gn = blockIdx.y * 128;
    GEMM_BODY(ao, wo, 1024)

    #pragma unroll
    for (int u = 0; u < 4; ++u) {
        int coll = wc * 64 + u * 16 + l16;
        float bb = bo[gn + coll];
        #pragma unroll
        for (int t = 0; t < 4; ++t)
            #pragma unroll
            for (int rr = 0; rr < 4; ++rr) {
                int row = R0 + wr * 64 + t * 16 + g * 4 + rr;
                out[(size_t)row * 1024 + gn + coll] = acc[t][u][rr] + bb;
            }
    }
}

// ------- Fused fragment materialization: z==0 fragify_v, z==1 rope_frag ---------
// Safe aliasing: z=0 reads v, writes vfrag(=ao buffer); z=1 reads q,k, writes
// qfrag(=xb), kfrag. No buffer is both read and written across z.
__global__ __launch_bounds__(256) void fragify_all_k(
    const unsigned short* __restrict__ qin, const unsigned short* __restrict__ kin,
    const unsigned short* __restrict__ v, const int* __restrict__ mask,
    unsigned short* __restrict__ qfrag, unsigned short* __restrict__ kfrag,
    unsigned short* __restrict__ vfrag)
{
    const int t = threadIdx.x;

    if (blockIdx.z == 0) {
        // ---- fragify_v: kt = x, bh = y ----
        __shared__ unsigned short Ld[64][72];
        __shared__ int Lm[64];
        const int kt = blockIdx.x, bh = blockIdx.y;   // bh = bz*16+h
        const int bz = bh >> 4, h = bh & 15;
        const int r = t & 63, c0 = (t >> 6) << 4;
        const unsigned short* srcp = &v[(size_t)(bz * Ss + kt * 64 + r) * 1024 + h * 64 + c0];
        *(ushort8*)&Ld[r][c0]     = *(const ushort8*)srcp;
        *(ushort8*)&Ld[r][c0 + 8] = *(const ushort8*)(srcp + 8);
        if (t < 64) Lm[t] = mask[bz * Ss + kt * 64 + t];
        __syncthreads();

        #pragma unroll
        for (int cc = 0; cc < 2; ++cc) {
            int c = t * 2 + cc;               // 0..511
            int dt4 = c >> 7, ks = (c >> 6) & 1, lane2 = c & 63;
            int gg = lane2 >> 4, ll = lane2 & 15;
            ushort8 o;
            #pragma unroll
            for (int e = 0; e < 8; ++e) {
                int key = ks * 32 + gg * 8 + e;
                o[e] = Lm[key] ? Ld[key][dt4 * 16 + ll] : (unsigned short)0;
            }
            *(ushort8*)&vfrag[(size_t)bh * 131072 + (size_t)kt * 4096 + (size_t)c * 8] = o;
        }
    } else {
        // ---- rope_frag: kt = x, hp = y&7, zz = y>>3 ----
        __shared__ unsigned short Ld[2][64][72];
        const int kt = blockIdx.x;
        const int hp = blockIdx.y & 7;
        const int zz = blockIdx.y >> 3;   // bit0 = bz, bit1 = sel
        const int bz = zz & 1, sel = zz >> 1;
        const unsigned short* src = sel ? kin : qin;
        unsigned short* dstf = sel ? kfrag : qfrag;

        const int r   = t & 63;
        const int c16 = (t >> 6) << 4;    // 0,16,32,48
        const int pos = kt * 64 + r;
        const size_t rowb = (size_t)(bz * Ss + pos) * 1024;

        ushort8 A0 = *(const ushort8*)&src[rowb + hp * 64 + c16];
        ushort8 A1 = *(const ushort8*)&src[rowb + hp * 64 + c16 + 8];
        ushort8 B0 = *(const ushort8*)&src[rowb + (hp + 8) * 64 + c16];
        ushort8 B1 = *(const ushort8*)&src[rowb + (hp + 8) * 64 + c16 + 8];

        #pragma unroll
        for (int i = 0; i < 16; ++i) {
            int d = c16 + i;
            float jj  = (float)(hp * 64 + d);
            float inv = exp2f(jj * -0.0259525632621414f);   // 10000^(-j/512)
            float ang = (float)pos * inv;
            float sn, cs;
            __sincosf(ang, &sn, &cs);
            unsigned short ua = (i < 8) ? A0[i] : A1[i - 8];
            unsigned short ub = (i < 8) ? B0[i] : B1[i - 8];
            float a = bf2f(ua), b = bf2f(ub);
            Ld[0][r][d] = f2bf(a * cs - b * sn);   // head hp   (low half j)
            Ld[1][r][d] = f2bf(b * cs + a * sn);   // head hp+8 (high half j+512)
        }
        __syncthreads();

        #pragma unroll
        for (int cc = 0; cc < 4; ++cc) {
            int c    = t * 4 + cc;            // 0..1023
            int hh   = c >> 9;                // head select
            int ci   = c & 511;               // chunk within head tile (0..511)
            int blk  = ci >> 7, s2 = (ci >> 6) & 1, lane2 = ci & 63;
            int gg = lane2 >> 4, ll = lane2 & 15;
            ushort8 o = *(const ushort8*)&Ld[hh][blk * 16 + ll][s2 * 32 + gg * 8];
            size_t base = (size_t)(bz * 16 + hp + hh * 8) * 131072 + (size_t)kt * 4096;
            *(ushort8*)&dstf[base + (size_t)ci * 8] = o;
        }
    }
}

// ---------------- Flash attention: rolled main loop (frozen best config) ---------
__global__ __launch_bounds__(256, 3) void flash_k(
    const unsigned short* __restrict__ qfrag, const unsigned short* __restrict__ kfrag,
    const unsigned short* __restrict__ vfrag, const unsigned short* __restrict__ maskbf,
    unsigned short* __restrict__ opart, float2* __restrict__ ml)
{
    // Bijective XCD remap: 1024 blocks = 8 XCDs x (4 (h,bz) groups x 16 qb x 2 half).
    const int F   = blockIdx.x;
    const int xcd = F & 7, j = F >> 3;          // j: 0..127
    const int grp = xcd * 4 + (j >> 5);         // 0..31
    const int rem = j & 31;
    const int qb  = rem >> 1;
    const int half = rem & 1;
    const int h   = grp & 15;
    const int bz  = grp >> 4;
    const int kt0 = half * 16;

    const int tid  = threadIdx.x;
    const int lane = tid & 63;
    const int w    = tid >> 6;
    const int l16  = lane & 15;
    const int g    = lane >> 4;

    const size_t fb = (size_t)(bz * 16 + h) * 131072;
    const unsigned short* kfb = kfrag + fb;
    const unsigned short* vfb = vfrag + fb;
    const unsigned short* qfb = qfrag + fb;

    // Running pointers (lane offsets baked in); advance one tile per iteration.
    const unsigned short* kp = kfb + (size_t)kt0 * 4096 + lane * 8;
    const unsigned short* vp = vfb + (size_t)kt0 * 4096 + lane * 8;
    const unsigned short* mp = maskbf + bz * Ss + kt0 * 64 + g * 8;

    // Q fragments (pre-scaled): blk16 = qb*8 + w*2 + t
    short8 qf[2][2];
    #pragma unroll
    for (int t = 0; t < 2; ++t)
        #pragma unroll
        for (int s = 0; s < 2; ++s)
            qf[t][s] = *(const short8*)&qfb[(size_t)(qb * 8 + w * 2 + t) * 1024
                                            + s * 512 + lane * 8];

    f32x4 O[2][4];
    #pragma unroll
    for (int t = 0; t < 2; ++t)
        #pragma unroll
        for (int d = 0; d < 4; ++d) O[t][d] = (f32x4)0.f;
    f32x4 Osum[2];
    Osum[0] = (f32x4)0.f; Osum[1] = (f32x4)0.f;
    float mrow[2] = {-1.0e4f, -1.0e4f};
    const f32x4 Zf = (f32x4)0.f;

    #pragma unroll 1
    for (int it = 0; it < 16; ++it) {
        // ---- K tile + mask (single-buffered) ----
        short8 KC[8];
        #pragma unroll
        for (int i = 0; i < 4; ++i) KC[i]     = *(const short8*)(kp + i * 512);
        #pragma unroll
        for (int i = 0; i < 4; ++i) KC[4 + i] = *(const short8*)(kp + 2048 + i * 512);
        short8 mf[2];
        mf[0] = *(const short8*)mp;
        mf[1] = *(const short8*)(mp + 32);

        // ---- S^T = K . Q^T ----
        f32x4 S[2][4];
        #pragma unroll
        for (int k4 = 0; k4 < 4; ++k4)
            #pragma unroll
            for (int t = 0; t < 2; ++t) {
                S[t][k4] = __builtin_amdgcn_mfma_f32_16x16x32_bf16(
                    KC[k4 * 2 + 0], qf[t][0], Zf, 0, 0, 0);
                S[t][k4] = __builtin_amdgcn_mfma_f32_16x16x32_bf16(
                    KC[k4 * 2 + 1], qf[t][1], S[t][k4], 0, 0, 0);
            }

        // ---- V ks=0 loads (latency under softmax) ----
        short8 V0[4];
        #pragma unroll
        for (int dt = 0; dt < 4; ++dt)
            V0[dt] = *(const short8*)(vp + dt * 1024);

        // ---- row max ----
        float rm[2];
        #pragma unroll
        for (int t = 0; t < 2; ++t) {
            float m0 = fmaxf(fmaxf(S[t][0][0], S[t][0][1]), fmaxf(S[t][0][2], S[t][0][3]));
            float m1 = fmaxf(fmaxf(S[t][1][0], S[t][1][1]), fmaxf(S[t][1][2], S[t][1][3]));
            float m2 = fmaxf(fmaxf(S[t][2][0], S[t][2][1]), fmaxf(S[t][2][2], S[t][2][3]));
            float m3 = fmaxf(fmaxf(S[t][3][0], S[t][3][1]), fmaxf(S[t][3][2], S[t][3][3]));
            float m  = fmaxf(fmaxf(m0, m1), fmaxf(m2, m3));
            m = fmaxf(m, __shfl_xor(m, 16));
            m = fmaxf(m, __shfl_xor(m, 32));
            rm[t] = m;
        }

        // ---- defer-max rescale ----
        bool grow = (rm[0] > mrow[0] + 10.0f) || (rm[1] > mrow[1] + 10.0f);
        if (__any((int)grow)) {
            float mn0 = fmaxf(mrow[0], rm[0]);
            float mn1 = fmaxf(mrow[1], rm[1]);
            float rs0 = exp2f(mrow[0] - mn0);
            float rs1 = exp2f(mrow[1] - mn1);
            mrow[0] = mn0; mrow[1] = mn1;
            #pragma unroll
            for (int r = 0; r < 4; ++r) {
                float f0 = __shfl(rs0, g * 4 + r);
                float f1 = __shfl(rs1, g * 4 + r);
                #pragma unroll
                for (int dt = 0; dt < 4; ++dt) { O[0][dt][r] *= f0; O[1][dt][r] *= f1; }
                Osum[0][r] *= f0; Osum[1][r] *= f1;
            }
        }

        // ---- V ks=1 loads (latency under pack + PV ks0) ----
        short8 V1[4];
        #pragma unroll
        for (int dt = 0; dt < 4; ++dt)
            V1[dt] = *(const short8*)(vp + 512 + dt * 1024);

        // ---- P = exp2(S - m), pack, redistribute, PV ----
        #pragma unroll
        for (int t = 0; t < 2; ++t) {
            unsigned int U[4][2];
            #pragma unroll
            for (int k4 = 0; k4 < 4; ++k4) {
                float p0 = exp2f(S[t][k4][0] - mrow[t]);
                float p1 = exp2f(S[t][k4][1] - mrow[t]);
                float p2 = exp2f(S[t][k4][2] - mrow[t]);
                float p3 = exp2f(S[t][k4][3] - mrow[t]);
                asm("v_cvt_pk_bf16_f32 %0, %1, %2" : "=v"(U[k4][0]) : "v"(p0), "v"(p1));
                asm("v_cvt_pk_bf16_f32 %0, %1, %2" : "=v"(U[k4][1]) : "v"(p2), "v"(p3));
            }
            asm("v_permlane32_swap_b32 %0, %1" : "+v"(U[0][0]), "+v"(U[1][0]));
            asm("v_permlane32_swap_b32 %0, %1" : "+v"(U[0][1]), "+v"(U[1][1]));
            asm("v_permlane32_swap_b32 %0, %1" : "+v"(U[2][0]), "+v"(U[3][0]));
            asm("v_permlane32_swap_b32 %0, %1" : "+v"(U[2][1]), "+v"(U[3][1]));
            asm("v_permlane16_swap_b32 %0, %1" : "+v"(U[0][0]), "+v"(U[1][0]));
            asm("v_permlane16_swap_b32 %0, %1" : "+v"(U[0][1]), "+v"(U[1][1]));
            asm("v_permlane16_swap_b32 %0, %1" : "+v"(U[2][0]), "+v"(U[3][0]));
            asm("v_permlane16_swap_b32 %0, %1" : "+v"(U[2][1]), "+v"(U[3][1]));

            u32x4 gp0, gp1;
            gp0[0] = U[0][0]; gp0[1] = U[0][1]; gp0[2] = U[1][0]; gp0[3] = U[1][1];
            gp1[0] = U[2][0]; gp1[1] = U[2][1]; gp1[2] = U[3][0]; gp1[3] = U[3][1];
            short8 pf0 = __builtin_bit_cast(short8, gp0);
            short8 pf1 = __builtin_bit_cast(short8, gp1);

            Osum[t] = __builtin_amdgcn_mfma_f32_16x16x32_bf16(pf0, mf[0], Osum[t], 0, 0, 0);
            #pragma unroll
            for (int dt = 0; dt < 4; ++dt)
                O[t][dt] = __builtin_amdgcn_mfma_f32_16x16x32_bf16(pf0, V0[dt], O[t][dt], 0, 0, 0);
            Osum[t] = __builtin_amdgcn_mfma_f32_16x16x32_bf16(pf1, mf[1], Osum[t], 0, 0, 0);
            #pragma unroll
            for (int dt = 0; dt < 4; ++dt)
                O[t][dt] = __builtin_amdgcn_mfma_f32_16x16x32_bf16(pf1, V1[dt], O[t][dt], 0, 0, 0);
        }

        kp += 4096; vp += 4096; mp += 64;
    }

    // ---- epilogue: normalized partial O (bf16) + per-query (m, sum) ----
    const size_t NE = (size_t)Mm * Hh;
    #pragma unroll
    for (int t = 0; t < 2; ++t)
        #pragma unroll
        for (int r = 0; r < 4; ++r) {
            float osum = Osum[t][r];
            float inv  = osum > 0.f ? 1.0f / osum : 0.f;
            float mo   = __shfl(mrow[t], g * 4 + r);   // S-layout m -> O-layout
            int rowl   = qb * 128 + w * 32 + t * 16 + g * 4 + r;   // 0..2047
            size_t ob  = (size_t)half * NE
                       + ((size_t)(bz * Ss + rowl)) * 1024 + h * 64;
            #pragma unroll
            for (int dt = 0; dt < 4; ++dt)
                opart[ob + dt * 16 + l16] = f2bf(O[t][dt][r] * inv);
            if (l16 == 0)
                ml[((half * 2 + bz) * 16 + h) * 2048 + rowl] = make_float2(mo, osum);
        }
}

// ---------------- Combine split-K halves (writes ao, after flash) ----------------
__global__ __launch_bounds__(256) void combine_k(
    const unsigned short* __restrict__ opart, const float2* __restrict__ ml,
    unsigned short* __restrict__ ao)
{
    const size_t NE = (size_t)Mm * Hh;
    int c    = blockIdx.x * 256 + threadIdx.x;   // 0..524287 (4096 rows x 128)
    int row  = c >> 7;                           // bz*2048 + qrow
    int col8 = c & 127;
    int h    = col8 >> 3;
    int bz   = row >> 11, qrow = row & 2047;

    float2 a = ml[((0 * 2 + bz) * 16 + h) * 2048 + qrow];
    float2 b = ml[((1 * 2 + bz) * 16 + h) * 2048 + qrow];
    float M  = fmaxf(a.x, b.x);
    float w1 = exp2f(a.x - M) * a.y;
    float w2 = exp2f(b.x - M) * b.y;
    float tot = w1 + w2;
    float inv = tot > 0.f ? 1.0f / tot : 0.f;
    w1 *= inv; w2 *= inv;

    ushort8 o1 = *(const ushort8*)&opart[(size_t)c * 8];
    ushort8 o2 = *(const ushort8*)&opart[NE + (size_t)c * 8];
    ushort8 o;
    #pragma unroll
    for (int jj = 0; jj < 8; ++jj)
        o[jj] = f2bf(bf2f(o1[jj]) * w1 + bf2f(o2[jj]) * w2);
    *(ushort8*)&ao[(size_t)c * 8] = o;
}

extern "C" void kernel_launch(void* const* d_in, const int* in_sizes, int n_in,
                              void* d_out, int out_size, void* d_ws, size_t ws_size,
                              hipStream_t stream)
{
    const float* x  = (const float*)d_in[0];
    const int*   am = (const int*)d_in[1];
    const float* Wq = (const float*)d_in[2];
    const float* bq = (const float*)d_in[3];
    const float* Wk = (const float*)d_in[4];
    const float* bk = (const float*)d_in[5];
    const float* Wv = (const float*)d_in[6];
    const float* bv = (const float*)d_in[7];
    const float* Wo = (const float*)d_in[8];
    const float* bo = (const float*)d_in[9];
    float* out = (float*)d_out;

    const size_t NE = (size_t)Mm * Hh;           // 4M elems
    unsigned short* q     = (unsigned short*)d_ws;
    unsigned short* k     = q + NE;
    unsigned short* v     = k + NE;
    unsigned short* ao    = v + NE;
    unsigned short* xb    = ao + NE;             // gemm input; reused as qfrag
    unsigned short* wall  = xb + NE;             // [Wq;Wk;Wv;Wo] rows
    unsigned short* wo    = wall + 3u * 1048576u;
    unsigned short* kfrag = wall + 4u * 1048576u;
    unsigned short* qfrag = xb;                  // xb dead after gemm_qkv
    unsigned short* vfrag = ao;                  // ao dead until combine_k
    unsigned short* opart = k;                   // k,v dead once frags built (16 MB)
    float2*         ml    = (float2*)(kfrag + 4u * 1048576u);   // 1 MB, 131072 entries
    unsigned short* maskbf = (unsigned short*)(ml + 131072);    // after ml's full extent

    convert_k<<<dim3(4096 + 2), 256, 0, stream>>>(
        x, Wq, Wk, Wv, Wo, am, xb, wall, maskbf);
    gemm_qkv_k<<<dim3(Mm / 128, 3072 / 128), 256, 0, stream>>>(
        xb, wall, bq, bk, bv, q, k, v);
    fragify_all_k<<<dim3(32, 32, 2), 256, 0, stream>>>(
        q, k, v, am, qfrag, kfrag, vfrag);
    flash_k<<<dim3(1024), 256, 0, stream>>>(qfrag, kfrag, vfrag, maskbf, opart, ml);
    combine_k<<<dim3((Mm * 128) / 256), 256, 0, stream>>>(opart, ml, ao);
    gemm_out_k<<<dim3(Mm / 128, Hh / 128), 256, 0, stream>>>(ao, wo, bo, out);
}